// Round 2
// baseline (1603.464 us; speedup 1.0000x reference)
//
#include <hip/hip_runtime.h>
#include <hip/hip_bf16.h>
#include <math.h>

#define B_   8
#define H_   128
#define W_   128
#define C_   256
#define SCALE_ 0.17677669529663687f   // 32^-0.5

// ---------------------------------------------------------------- K1: LayerNorm + cyclic shift(-4,-4)
__global__ __launch_bounds__(256) void k_ln_shift(
    const float* __restrict__ x, const float* __restrict__ g,
    const float* __restrict__ b, float* __restrict__ xn) {
  int lane = threadIdx.x & 63;
  int tok  = (blockIdx.x << 2) + (threadIdx.x >> 6);
  int bb = tok >> 14;
  int h  = (tok >> 7) & 127;
  int w  = tok & 127;
  const float4* xp = (const float4*)(x + ((size_t)tok << 8));
  float4 v = xp[lane];
  float s  = v.x + v.y + v.z + v.w;
  float s2 = v.x*v.x + v.y*v.y + v.z*v.z + v.w*v.w;
#pragma unroll
  for (int o = 32; o >= 1; o >>= 1) {
    s  += __shfl_xor(s, o);
    s2 += __shfl_xor(s2, o);
  }
  float mu = s * (1.0f/256.0f);
  float var = s2 * (1.0f/256.0f) - mu*mu;
  float rs = rsqrtf(fmaxf(var, 0.0f) + 1e-5f);
  float4 gv = ((const float4*)g)[lane];
  float4 bv = ((const float4*)b)[lane];
  float4 o;
  o.x = (v.x - mu)*rs*gv.x + bv.x;
  o.y = (v.y - mu)*rs*gv.y + bv.y;
  o.z = (v.z - mu)*rs*gv.z + bv.z;
  o.w = (v.w - mu)*rs*gv.w + bv.w;
  int hs = (h + 124) & 127;
  int ws2 = (w + 124) & 127;
  float4* op = (float4*)(xn + ((((size_t)bb*H_ + hs)*W_ + ws2) << 8));
  op[lane] = o;
}

// ---------------------------------------------------------------- K2: depthwise 7x7 conv (pad 3), shifted domain
__global__ __launch_bounds__(256) void k_dwconv(
    const float* __restrict__ xn, const float* __restrict__ wgt,
    const float* __restrict__ bias, float* __restrict__ dw) {
  __shared__ float tile[14][14][64];
  int tid = threadIdx.x;
  int x0 = blockIdx.x * 8, y0 = blockIdx.y * 8;
  int bb = blockIdx.z >> 2, cg = blockIdx.z & 3;
  int cbase = cg * 64;
  for (int idx = tid; idx < 14*14*16; idx += 256) {
    int c4 = idx & 15;
    int t  = idx >> 4;
    int xx = t % 14, yy = t / 14;
    int gy = y0 + yy - 3, gx = x0 + xx - 3;
    float4 v; v.x = v.y = v.z = v.w = 0.0f;
    if (gy >= 0 && gy < H_ && gx >= 0 && gx < W_)
      v = *(const float4*)(xn + ((((size_t)bb*H_ + gy)*W_ + gx) << 8) + cbase + (c4 << 2));
    *(float4*)&tile[yy][xx][c4 << 2] = v;
  }
  int cl = tid & 63;
  int sp = tid >> 6;
  int c  = cbase + cl;
  float wr[49];
#pragma unroll
  for (int i = 0; i < 49; ++i) wr[i] = wgt[c*49 + i];
  float bv = bias[c];
  __syncthreads();
  for (int q = 0; q < 16; ++q) {
    int p  = sp*16 + q;
    int py = p >> 3, px = p & 7;
    float acc = bv;
#pragma unroll
    for (int ky = 0; ky < 7; ++ky)
#pragma unroll
      for (int kx = 0; kx < 7; ++kx)
        acc += tile[py+ky][px+kx][cl] * wr[ky*7+kx];
    dw[((((size_t)bb*H_ + y0+py)*W_ + x0+px) << 8) + c] = acc;
  }
}

// ---------------------------------------------------------------- K3: fused QKV-GEMM + window attention, per window
// One block per window. Reads xn; accumulates attention output INTO dwa (dw buffer).
__global__ __launch_bounds__(256) void k_qkvattn(
    const float* __restrict__ xn, const float* __restrict__ qkvw,
    const float* __restrict__ qkvb, const float* __restrict__ mask,
    const float* __restrict__ rpb, float* __restrict__ dwa) {
  __shared__ __hip_bfloat16 Xs[64][260];   // 33,280 B
  __shared__ __hip_bfloat16 qs[64][36];    //  4,608 B
  __shared__ __hip_bfloat16 ks2[64][36];   //  4,608 B
  __shared__ __hip_bfloat16 vs2[64][36];   //  4,608 B
  __shared__ float ps[64][65];             // 16,640 B; doubles as Bs[32][100] during QKV GEMM
  float* Bs = &ps[0][0];

  int t = threadIdx.x;
  int win = blockIdx.x;
  int bb = win >> 8, wy = (win >> 4) & 15, wx = win & 15;

  { // stage X window (64 tokens x 256 ch) as bf16
    int r = t >> 2, c0 = (t & 3) << 6;
    int th = wy*8 + (r >> 3), tw = wx*8 + (r & 7);
    const float* src = xn + ((((size_t)bb*H_ + th)*W_ + tw) << 8) + c0;
#pragma unroll
    for (int c = 0; c < 64; c += 4) {
      float4 v = *(const float4*)(src + c);
      Xs[r][c0+c+0] = __float2bfloat16(v.x);
      Xs[r][c0+c+1] = __float2bfloat16(v.y);
      Xs[r][c0+c+2] = __float2bfloat16(v.z);
      Xs[r][c0+c+3] = __float2bfloat16(v.w);
    }
  }

  int ty = t >> 4, tx = t & 15;
  int i0 = ty << 2;

  for (int h = 0; h < 8; ++h) {
    // ---- QKV GEMM for head h: [64 tok] x [96 cols: q|k|v], K=256
    float acc[4][6] = {};
    for (int k0 = 0; k0 < 256; k0 += 32) {
      __syncthreads();   // Bs/ps free of prior readers (also covers initial Xs visibility)
      for (int idx = t; idx < 768; idx += 256) {  // 96 rows x 8 float4
        int row = idx >> 3, kq = (idx & 7) << 2;
        int wrow = ((row >> 5) << 8) + (h << 5) + (row & 31);
        float4 v = *(const float4*)(qkvw + (size_t)wrow*256 + k0 + kq);
        Bs[(kq+0)*100 + row] = v.x;
        Bs[(kq+1)*100 + row] = v.y;
        Bs[(kq+2)*100 + row] = v.z;
        Bs[(kq+3)*100 + row] = v.w;
      }
      __syncthreads();
#pragma unroll 4
      for (int k = 0; k < 32; ++k) {
        float a[4], b[6];
#pragma unroll
        for (int ii = 0; ii < 4; ++ii) a[ii] = __bfloat162float(Xs[i0+ii][k0+k]);
#pragma unroll
        for (int jj = 0; jj < 6; ++jj) b[jj] = Bs[k*100 + tx*6 + jj];
#pragma unroll
        for (int ii = 0; ii < 4; ++ii)
#pragma unroll
          for (int jj = 0; jj < 6; ++jj)
            acc[ii][jj] += a[ii] * b[jj];
      }
    }
    // epilogue: bias, scale q, write bf16 q/k/v
#pragma unroll
    for (int ii = 0; ii < 4; ++ii)
#pragma unroll
      for (int jj = 0; jj < 6; ++jj) {
        int col = tx*6 + jj;
        int which = col >> 5, d = col & 31;
        float v = acc[ii][jj] + qkvb[(which << 8) + (h << 5) + d];
        if (which == 0) v *= SCALE_;
        __hip_bfloat16 bv = __float2bfloat16(v);
        if (which == 0)      qs[i0+ii][d]  = bv;
        else if (which == 1) ks2[i0+ii][d] = bv;
        else                 vs2[i0+ii][d] = bv;
      }
    __syncthreads();   // q/k/v visible; all Bs reads done -> ps reusable

    // ---- p = q k^T + rpb + mask
    int j0 = tx << 2;
    float pacc[4][4] = {};
#pragma unroll 8
    for (int d = 0; d < 32; ++d) {
      float qa[4], kb[4];
#pragma unroll
      for (int ii = 0; ii < 4; ++ii) qa[ii] = __bfloat162float(qs[i0+ii][d]);
#pragma unroll
      for (int jj = 0; jj < 4; ++jj) kb[jj] = __bfloat162float(ks2[j0+jj][d]);
#pragma unroll
      for (int ii = 0; ii < 4; ++ii)
#pragma unroll
        for (int jj = 0; jj < 4; ++jj)
          pacc[ii][jj] += qa[ii]*kb[jj];
    }
    const float* mrow = mask + ((size_t)(win & 255) << 12);
#pragma unroll
    for (int ii = 0; ii < 4; ++ii) {
      int i = i0+ii, yi = i >> 3, xi = i & 7;
#pragma unroll
      for (int jj = 0; jj < 4; ++jj) {
        int j = j0+jj, yj = j >> 3, xj = j & 7;
        int rel = (yi-yj+7)*15 + (xi-xj+7);
        ps[i][j] = pacc[ii][jj] + rpb[rel*8 + h] + mrow[i*64 + j];
      }
    }
    __syncthreads();

    { // softmax over rows (4 threads per row)
      int row = t >> 2, l4 = t & 3;
      float vals[16], mx = -3.4e38f;
#pragma unroll
      for (int jj = 0; jj < 16; ++jj) { vals[jj] = ps[row][(jj<<2)+l4]; mx = fmaxf(mx, vals[jj]); }
      mx = fmaxf(mx, __shfl_xor(mx, 1));
      mx = fmaxf(mx, __shfl_xor(mx, 2));
      float sum = 0.f;
#pragma unroll
      for (int jj = 0; jj < 16; ++jj) { vals[jj] = __expf(vals[jj]-mx); sum += vals[jj]; }
      sum += __shfl_xor(sum, 1);
      sum += __shfl_xor(sum, 2);
      float rinv = 1.0f/sum;
#pragma unroll
      for (int jj = 0; jj < 16; ++jj) ps[row][(jj<<2)+l4] = vals[jj]*rinv;
    }
    __syncthreads();

    { // out = P @ V, accumulate into dwa (single owner per location)
      int d0 = tx << 1;
      float o[4][2] = {};
      for (int j = 0; j < 64; ++j) {
        float v0 = __bfloat162float(vs2[j][d0]);
        float v1 = __bfloat162float(vs2[j][d0+1]);
#pragma unroll
        for (int ii = 0; ii < 4; ++ii) {
          float pp = ps[i0+ii][j];
          o[ii][0] += pp*v0; o[ii][1] += pp*v1;
        }
      }
#pragma unroll
      for (int ii = 0; ii < 4; ++ii) {
        int tok = i0+ii;
        int th = wy*8 + (tok >> 3), tw = wx*8 + (tok & 7);
        float* dst = dwa + ((((size_t)bb*H_ + th)*W_ + tw) << 8) + (h << 5) + d0;
        float2 dv = *(const float2*)dst;
        float2 ov; ov.x = o[ii][0] + dv.x; ov.y = o[ii][1] + dv.y;
        *(float2*)dst = ov;
      }
    }
    __syncthreads();   // protect vs2/ps before next head overwrites
  }
}

// ---------------------------------------------------------------- K4: proj GEMM + bias + unshift + residual
// A (= att+dw) in spatial/shifted layout; writes final output at unshifted coords.
__global__ __launch_bounds__(256) void k_proj(
    const float* __restrict__ A, const float* __restrict__ wp,
    const float* __restrict__ bp, const float* __restrict__ x,
    float* __restrict__ out) {
  __shared__ float As[16][68];
  __shared__ float Bsh[16][68];
  int t   = threadIdx.x;
  int nb  = blockIdx.x;    // 0..3
  int tb  = blockIdx.y;    // 0..2047 (64-token block in shifted order)
  int r  = t >> 2, kq = (t & 3) << 2;
  int tok = tb*64 + r;
  const float* arow = A + ((size_t)tok << 8);
  const float* brow = wp + (size_t)(nb*64 + r) * 256;
  int ty = t >> 4, tx = t & 15;
  float acc[4][4] = {};
  for (int kb = 0; kb < 16; ++kb) {
    float4 av = *(const float4*)(arow + kb*16 + kq);
    float4 bv = *(const float4*)(brow + kb*16 + kq);
    As[kq+0][r] = av.x; As[kq+1][r] = av.y; As[kq+2][r] = av.z; As[kq+3][r] = av.w;
    Bsh[kq+0][r] = bv.x; Bsh[kq+1][r] = bv.y; Bsh[kq+2][r] = bv.z; Bsh[kq+3][r] = bv.w;
    __syncthreads();
#pragma unroll
    for (int kk = 0; kk < 16; ++kk) {
      float4 a = *(const float4*)&As[kk][ty << 2];
      float4 bf = *(const float4*)&Bsh[kk][tx << 2];
      float ar[4] = {a.x, a.y, a.z, a.w};
      float br[4] = {bf.x, bf.y, bf.z, bf.w};
#pragma unroll
      for (int ii = 0; ii < 4; ++ii)
#pragma unroll
        for (int jj = 0; jj < 4; ++jj)
          acc[ii][jj] += ar[ii] * br[jj];
    }
    __syncthreads();
  }
  int jb = nb*64 + (tx << 2);
  float4 p4 = *(const float4*)(bp + jb);
#pragma unroll
  for (int ii = 0; ii < 4; ++ii) {
    int n = (ty << 2) + ii;
    int tok2 = tb*64 + n;
    int bb2 = tok2 >> 14, hh = (tok2 >> 7) & 127, ww = tok2 & 127;
    int ho = (hh + 4) & 127;
    int wo = (ww + 4) & 127;
    size_t oidx = ((((size_t)bb2*H_ + ho)*W_ + wo) << 8) + jb;
    float4 s4 = *(const float4*)(x + oidx);
    float4 o;
    o.x = acc[ii][0] + p4.x + s4.x;
    o.y = acc[ii][1] + p4.y + s4.y;
    o.z = acc[ii][2] + p4.z + s4.z;
    o.w = acc[ii][3] + p4.w + s4.w;
    *(float4*)(out + oidx) = o;
  }
}

extern "C" void kernel_launch(void* const* d_in, const int* in_sizes, int n_in,
                              void* d_out, int out_size, void* d_ws, size_t ws_size,
                              hipStream_t stream) {
  (void)in_sizes; (void)n_in; (void)out_size; (void)ws_size;
  const float* x     = (const float*)d_in[0];
  const float* mask  = (const float*)d_in[1];
  // d_in[2] = x_size (scalar) -- shapes hardcoded
  const float* g     = (const float*)d_in[3];
  const float* bln   = (const float*)d_in[4];
  const float* dww   = (const float*)d_in[5];
  const float* dwb   = (const float*)d_in[6];
  const float* qkvw  = (const float*)d_in[7];
  const float* qkvb  = (const float*)d_in[8];
  const float* projw = (const float*)d_in[9];
  const float* projb = (const float*)d_in[10];
  const float* rpb   = (const float*)d_in[11];

  float* xn    = (float*)d_out;   // d_out doubles as xn scratch; fully rewritten by k_proj
  float* dwbuf = (float*)d_ws;    // 128 MiB: dw, then dw+att
  float* outp  = (float*)d_out;

  k_ln_shift<<<dim3(32768),        dim3(256), 0, stream>>>(x, g, bln, xn);
  k_dwconv  <<<dim3(16, 16, B_*4), dim3(256), 0, stream>>>(xn, dww, dwb, dwbuf);
  k_qkvattn <<<dim3(2048),         dim3(256), 0, stream>>>(xn, qkvw, qkvb, mask, rpb, dwbuf);
  k_proj    <<<dim3(4, 2048),      dim3(256), 0, stream>>>(dwbuf, projw, projb, x, outp);
}

// Round 3
// 847.405 us; speedup vs baseline: 1.8922x; 1.8922x over previous
//
#include <hip/hip_runtime.h>
#include <hip/hip_bf16.h>
#include <math.h>

#define B_ 8
#define SCALE_ 0.17677669529663687f   // 32^-0.5

typedef __attribute__((ext_vector_type(8))) short s8v;
typedef __attribute__((ext_vector_type(4))) float f4v;

__device__ __forceinline__ unsigned short f2bf(float f) {
  unsigned int u = __float_as_uint(f);
  u += 0x7fffu + ((u >> 16) & 1u);
  return (unsigned short)(u >> 16);
}
__device__ __forceinline__ float bf2f(unsigned short h) {
  return __uint_as_float(((unsigned int)h) << 16);
}

// ---------------------------------------------------------------- K0: weights f32 -> bf16 (once)
__global__ __launch_bounds__(256) void k_wcvt(const float* __restrict__ qkvw,
    const float* __restrict__ projw, unsigned short* __restrict__ wb) {
  int id = blockIdx.x * 256 + threadIdx.x;   // 0..32767
  int i = id * 8;
  const float* src = (i < 196608) ? (qkvw + i) : (projw + (i - 196608));
  float4 a = *(const float4*)src;
  float4 b = *(const float4*)(src + 4);
  unsigned short o[8];
  o[0]=f2bf(a.x); o[1]=f2bf(a.y); o[2]=f2bf(a.z); o[3]=f2bf(a.w);
  o[4]=f2bf(b.x); o[5]=f2bf(b.y); o[6]=f2bf(b.z); o[7]=f2bf(b.w);
  float4* d = (float4*)(wb + i);
  *d = *(float4*)o;
}

// ---------------------------------------------------------------- K1: per-token LN stats (mu, rsqrt)
__global__ __launch_bounds__(256) void k_musig(const float* __restrict__ x,
                                               float2* __restrict__ musig) {
  int lane = threadIdx.x & 63;
  int tok = blockIdx.x * 4 + (threadIdx.x >> 6);
  float4 v = *(const float4*)(x + ((size_t)tok << 8) + (lane << 2));
  float s  = v.x + v.y + v.z + v.w;
  float s2 = v.x*v.x + v.y*v.y + v.z*v.z + v.w*v.w;
#pragma unroll
  for (int o = 32; o >= 1; o >>= 1) { s += __shfl_xor(s, o); s2 += __shfl_xor(s2, o); }
  float mu  = s * (1.0f/256.0f);
  float var = s2 * (1.0f/256.0f) - mu*mu;
  float rs  = rsqrtf(fmaxf(var, 0.0f) + 1e-5f);
  if (lane == 0) musig[tok] = make_float2(mu, rs);
}

// ---------------------------------------------------------------- K2: depthwise 7x7 conv on LN'd shifted map
// block: 8x8 shifted-spatial (== one window) x 64 channels; reads x+musig, writes dwb bf16 window-ordered
__global__ __launch_bounds__(256) void k_dwconv(
    const float* __restrict__ x, const float2* __restrict__ musig,
    const float* __restrict__ gma, const float* __restrict__ bta,
    const float* __restrict__ wgt, const float* __restrict__ bias,
    unsigned short* __restrict__ dwb) {
  __shared__ float tile[14][14][64];
  int tid = threadIdx.x;
  int bx = blockIdx.x, by = blockIdx.y;
  int x0 = bx * 8, y0 = by * 8;
  int bb = blockIdx.z >> 2, cg = blockIdx.z & 3;
  int cbase = cg << 6;
  for (int idx = tid; idx < 14*14*16; idx += 256) {
    int c4 = idx & 15;
    int sp = idx >> 4;
    int xx = sp % 14, yy = sp / 14;
    int gy = y0 + yy - 3, gx = x0 + xx - 3;   // shifted coords
    float4 v; v.x = v.y = v.z = v.w = 0.0f;
    if (gy >= 0 && gy < 128 && gx >= 0 && gx < 128) {
      int oy = (gy + 4) & 127, ox = (gx + 4) & 127;   // original coords
      float4 xv = *(const float4*)(x + ((((size_t)(bb*128 + oy))*128 + ox) << 8) + cbase + (c4 << 2));
      float2 ms = musig[bb*16384 + oy*128 + ox];
      float4 gv = *(const float4*)(gma + cbase + (c4 << 2));
      float4 bv = *(const float4*)(bta + cbase + (c4 << 2));
      v.x = (xv.x - ms.x)*ms.y*gv.x + bv.x;
      v.y = (xv.y - ms.x)*ms.y*gv.y + bv.y;
      v.z = (xv.z - ms.x)*ms.y*gv.z + bv.z;
      v.w = (xv.w - ms.x)*ms.y*gv.w + bv.w;
    }
    *(float4*)&tile[yy][xx][c4 << 2] = v;
  }
  int cl = tid & 63, sp2 = tid >> 6;
  int c = cbase + cl;
  float wr[49];
#pragma unroll
  for (int i = 0; i < 49; ++i) wr[i] = wgt[c*49 + i];
  float bv = bias[c];
  __syncthreads();
  int win = bb*256 + by*16 + bx;
  for (int qq = 0; qq < 16; ++qq) {
    int p  = sp2*16 + qq;
    int py = p >> 3, px = p & 7;
    float acc = bv;
#pragma unroll
    for (int ky = 0; ky < 7; ++ky)
#pragma unroll
      for (int kx = 0; kx < 7; ++kx)
        acc += tile[py+ky][px+kx][cl] * wr[ky*7+kx];
    dwb[((size_t)win*64 + py*8 + px)*256 + c] = f2bf(acc);
  }
}

// ---------------------------------------------------------------- K3: mega — LN-restage + QKV GEMM + attn + proj (MFMA)
// One block per window, 4 waves; wave w owns heads 2w, 2w+1.
// MFMA 16x16x32 bf16 layouts: A[l&15][(l>>4)*8+j]; B[(l>>4)*8+j][l&15]; C/D row=(l>>4)*4+r, col=l&15.
__global__ __launch_bounds__(256, 2) void k_mega(
    const float* __restrict__ x, const float2* __restrict__ musig,
    const float* __restrict__ gma, const float* __restrict__ bta,
    const unsigned short* __restrict__ wqb, const float* __restrict__ qkvb,
    const unsigned short* __restrict__ wpb, const float* __restrict__ projb,
    const float* __restrict__ mask, const float* __restrict__ rpb,
    const unsigned short* __restrict__ dwb, float* __restrict__ out) {
  // LDS: Xs [64][136] bf16 (one 128-wide K half)  = 17408 B at SM+0
  //      per-wave bufs 2 x [64][40] bf16 (5120 B) = 40960 B at SM+8704 (ushort units)
  //      A2 [64][264] bf16 aliases SM+0 after attention barrier
  __shared__ unsigned short SM[29184];
  int t = threadIdx.x;
  int wv = t >> 6, lane = t & 63, g = lane >> 4, q = lane & 15;
  int win = blockIdx.x;
  int bb = win >> 8, wy = (win >> 4) & 15, wx = win & 15;

  unsigned short* Xs   = SM;
  unsigned short* bufA = SM + 8704 + (wv*2 + 0)*2560;
  unsigned short* bufB = SM + 8704 + (wv*2 + 1)*2560;

  f4v oacc[2][4][2];
#pragma unroll
  for (int a = 0; a < 2; ++a)
#pragma unroll
    for (int b = 0; b < 4; ++b)
#pragma unroll
      for (int c = 0; c < 2; ++c)
        oacc[a][b][c] = f4v{0.f, 0.f, 0.f, 0.f};

  // stage one 128-wide K half of the LN'd window into Xs
  auto stage = [&](int kh) {
    __syncthreads();
    int tok = t >> 2, cq = (t & 3) << 5;
    int iy = tok >> 3, ix = tok & 7;
    int oy = (wy*8 + iy + 4) & 127, ox = (wx*8 + ix + 4) & 127;
    const float* xr = x + ((((size_t)(bb*128 + oy))*128 + ox) << 8) + kh*128 + cq;
    float2 ms = musig[bb*16384 + oy*128 + ox];
    const float* gp = gma + kh*128 + cq;
    const float* bp = bta + kh*128 + cq;
#pragma unroll
    for (int c = 0; c < 32; c += 8) {
      float4 v0 = *(const float4*)(xr + c);
      float4 v1 = *(const float4*)(xr + c + 4);
      float4 g0 = *(const float4*)(gp + c);
      float4 g1 = *(const float4*)(gp + c + 4);
      float4 b0 = *(const float4*)(bp + c);
      float4 b1 = *(const float4*)(bp + c + 4);
      unsigned short o[8];
      o[0] = f2bf((v0.x - ms.x)*ms.y*g0.x + b0.x);
      o[1] = f2bf((v0.y - ms.x)*ms.y*g0.y + b0.y);
      o[2] = f2bf((v0.z - ms.x)*ms.y*g0.z + b0.z);
      o[3] = f2bf((v0.w - ms.x)*ms.y*g0.w + b0.w);
      o[4] = f2bf((v1.x - ms.x)*ms.y*g1.x + b1.x);
      o[5] = f2bf((v1.y - ms.x)*ms.y*g1.y + b1.y);
      o[6] = f2bf((v1.z - ms.x)*ms.y*g1.z + b1.z);
      o[7] = f2bf((v1.w - ms.x)*ms.y*g1.w + b1.w);
      *(float4*)(Xs + tok*136 + cq + c) = *(float4*)o;
    }
    __syncthreads();
  };

  for (int hl = 0; hl < 2; ++hl) {
    int h = wv*2 + hl;
    // ---- GEMM1: this head's Q|K (64x64) and V (64x32), K=256 in two halves
    f4v acc[4][4], accv[4][2];
#pragma unroll
    for (int mi = 0; mi < 4; ++mi) {
#pragma unroll
      for (int nj = 0; nj < 4; ++nj) acc[mi][nj] = f4v{0.f,0.f,0.f,0.f};
#pragma unroll
      for (int nv = 0; nv < 2; ++nv) accv[mi][nv] = f4v{0.f,0.f,0.f,0.f};
    }
    for (int kh = 0; kh < 2; ++kh) {
      stage(kh);
      int ko = kh*128 + g*8;
      const unsigned short* wq0 = wqb + (size_t)(h*32 + q)*256 + ko;          // Q rows
      const unsigned short* wk0 = wqb + (size_t)(256 + h*32 + q)*256 + ko;    // K rows
      const unsigned short* wv0 = wqb + (size_t)(512 + h*32 + q)*256 + ko;    // V rows
#pragma unroll
      for (int ks = 0; ks < 4; ++ks) {
        int kb = ks*32;
        s8v af[4];
#pragma unroll
        for (int mi = 0; mi < 4; ++mi)
          af[mi] = *(const s8v*)(Xs + (mi*16 + q)*136 + kb + g*8);
        s8v bq0 = *(const s8v*)(wq0 + kb);
        s8v bq1 = *(const s8v*)(wq0 + 16*256 + kb);
        s8v bk0 = *(const s8v*)(wk0 + kb);
        s8v bk1 = *(const s8v*)(wk0 + 16*256 + kb);
        s8v bv0 = *(const s8v*)(wv0 + kb);
        s8v bv1 = *(const s8v*)(wv0 + 16*256 + kb);
#pragma unroll
        for (int mi = 0; mi < 4; ++mi) {
          acc[mi][0]  = __builtin_amdgcn_mfma_f32_16x16x32_bf16(af[mi], bq0, acc[mi][0], 0, 0, 0);
          acc[mi][1]  = __builtin_amdgcn_mfma_f32_16x16x32_bf16(af[mi], bq1, acc[mi][1], 0, 0, 0);
          acc[mi][2]  = __builtin_amdgcn_mfma_f32_16x16x32_bf16(af[mi], bk0, acc[mi][2], 0, 0, 0);
          acc[mi][3]  = __builtin_amdgcn_mfma_f32_16x16x32_bf16(af[mi], bk1, acc[mi][3], 0, 0, 0);
          accv[mi][0] = __builtin_amdgcn_mfma_f32_16x16x32_bf16(af[mi], bv0, accv[mi][0], 0, 0, 0);
          accv[mi][1] = __builtin_amdgcn_mfma_f32_16x16x32_bf16(af[mi], bv1, accv[mi][1], 0, 0, 0);
        }
      }
    }
    // ---- epilogue: Q -> bufA [64][40] (scaled), K -> bufB [64][40]
    float b0 = qkvb[h*32 + q],        b1 = qkvb[h*32 + 16 + q];
    float b2 = qkvb[256 + h*32 + q],  b3 = qkvb[256 + h*32 + 16 + q];
#pragma unroll
    for (int mi = 0; mi < 4; ++mi)
#pragma unroll
      for (int r = 0; r < 4; ++r) {
        int tok = mi*16 + g*4 + r;
        bufA[tok*40 + q]      = f2bf((acc[mi][0][r] + b0) * SCALE_);
        bufA[tok*40 + 16 + q] = f2bf((acc[mi][1][r] + b1) * SCALE_);
        bufB[tok*40 + q]      = f2bf(acc[mi][2][r] + b2);
        bufB[tok*40 + 16 + q] = f2bf(acc[mi][3][r] + b3);
      }
    // ---- S = Q K^T (k-dim = 32, single MFMA step)
    f4v s[4][4];
#pragma unroll
    for (int mi = 0; mi < 4; ++mi)
#pragma unroll
      for (int nj = 0; nj < 4; ++nj) s[mi][nj] = f4v{0.f,0.f,0.f,0.f};
    {
      s8v qa[4], kb2[4];
#pragma unroll
      for (int mi = 0; mi < 4; ++mi)
        qa[mi] = *(const s8v*)(bufA + (mi*16 + q)*40 + g*8);
#pragma unroll
      for (int nj = 0; nj < 4; ++nj)
        kb2[nj] = *(const s8v*)(bufB + (nj*16 + q)*40 + g*8);
#pragma unroll
      for (int mi = 0; mi < 4; ++mi)
#pragma unroll
        for (int nj = 0; nj < 4; ++nj)
          s[mi][nj] = __builtin_amdgcn_mfma_f32_16x16x32_bf16(qa[mi], kb2[nj], s[mi][nj], 0, 0, 0);
    }
    // ---- V epilogue: Vt[32 d][72 pitch] transposed into bufA (Q now dead)
    {
      float bv_0 = qkvb[512 + h*32 + q], bv_1 = qkvb[512 + h*32 + 16 + q];
#pragma unroll
      for (int mi = 0; mi < 4; ++mi)
#pragma unroll
        for (int r = 0; r < 4; ++r) {
          int tok = mi*16 + g*4 + r;
          bufA[(q)*72 + tok]      = f2bf(accv[mi][0][r] + bv_0);
          bufA[(16 + q)*72 + tok] = f2bf(accv[mi][1][r] + bv_1);
        }
    }
    // ---- bias + mask, softmax over rows (rows live in 16-lane groups)
    const float* mwin = mask + (size_t)(win & 255)*4096;
#pragma unroll
    for (int mi = 0; mi < 4; ++mi)
#pragma unroll
      for (int nj = 0; nj < 4; ++nj)
#pragma unroll
        for (int r = 0; r < 4; ++r) {
          int i = mi*16 + g*4 + r, j = nj*16 + q;
          int rel = ((i>>3) - (j>>3) + 7)*15 + ((i&7) - (j&7) + 7);
          s[mi][nj][r] += rpb[rel*8 + h] + mwin[i*64 + j];
        }
    float rin[4][4];
#pragma unroll
    for (int mi = 0; mi < 4; ++mi)
#pragma unroll
      for (int r = 0; r < 4; ++r) {
        float m0 = fmaxf(fmaxf(s[mi][0][r], s[mi][1][r]), fmaxf(s[mi][2][r], s[mi][3][r]));
        m0 = fmaxf(m0, __shfl_xor(m0, 1));
        m0 = fmaxf(m0, __shfl_xor(m0, 2));
        m0 = fmaxf(m0, __shfl_xor(m0, 4));
        m0 = fmaxf(m0, __shfl_xor(m0, 8));
        float sm = 0.f;
#pragma unroll
        for (int nj = 0; nj < 4; ++nj) {
          s[mi][nj][r] = __expf(s[mi][nj][r] - m0);
          sm += s[mi][nj][r];
        }
        sm += __shfl_xor(sm, 1);
        sm += __shfl_xor(sm, 2);
        sm += __shfl_xor(sm, 4);
        sm += __shfl_xor(sm, 8);
        rin[mi][r] = 1.0f / sm;
      }
    // ---- P (bf16, k-half at a time into bufB; K dead) and PV
    for (int half = 0; half < 2; ++half) {
#pragma unroll
      for (int mi = 0; mi < 4; ++mi)
#pragma unroll
        for (int nl = 0; nl < 2; ++nl)
#pragma unroll
          for (int r = 0; r < 4; ++r) {
            int i = mi*16 + g*4 + r;
            bufB[i*40 + nl*16 + q] = f2bf(s[mi][half*2 + nl][r] * rin[mi][r]);
          }
      s8v pa[4], vb[2];
#pragma unroll
      for (int mi = 0; mi < 4; ++mi)
        pa[mi] = *(const s8v*)(bufB + (mi*16 + q)*40 + g*8);
#pragma unroll
      for (int nv = 0; nv < 2; ++nv)
        vb[nv] = *(const s8v*)(bufA + (nv*16 + q)*72 + half*32 + g*8);
#pragma unroll
      for (int mi = 0; mi < 4; ++mi)
#pragma unroll
        for (int nv = 0; nv < 2; ++nv)
          oacc[hl][mi][nv] = __builtin_amdgcn_mfma_f32_16x16x32_bf16(pa[mi], vb[nv], oacc[hl][mi][nv], 0, 0, 0);
    }
  }

  // ---- A2 = attn_out + dw  (bf16 [64][264], aliases Xs + wave bufs)
  __syncthreads();
  unsigned short* A2 = SM;
#pragma unroll
  for (int hl = 0; hl < 2; ++hl)
#pragma unroll
    for (int mi = 0; mi < 4; ++mi)
#pragma unroll
      for (int nv = 0; nv < 2; ++nv)
#pragma unroll
        for (int r = 0; r < 4; ++r) {
          int tok = mi*16 + g*4 + r;
          int ch = (wv*2 + hl)*32 + nv*16 + q;
          float dv = bf2f(dwb[((size_t)win*64 + tok)*256 + ch]);
          A2[tok*264 + ch] = f2bf(oacc[hl][mi][nv][r] + dv);
        }
  __syncthreads();

  // ---- GEMM2: Y = A2 * Wp^T  (wave w -> cols 64w..64w+63), + bias + unshift + residual
  f4v c2[4][4];
#pragma unroll
  for (int mi = 0; mi < 4; ++mi)
#pragma unroll
    for (int nj = 0; nj < 4; ++nj) c2[mi][nj] = f4v{0.f,0.f,0.f,0.f};
  const unsigned short* wp0 = wpb + (size_t)(wv*64 + q)*256 + g*8;
#pragma unroll
  for (int ks = 0; ks < 8; ++ks) {
    int kb = ks*32;
    s8v a2f[4];
#pragma unroll
    for (int mi = 0; mi < 4; ++mi)
      a2f[mi] = *(const s8v*)(A2 + (mi*16 + q)*264 + kb + g*8);
    s8v b2f[4];
#pragma unroll
    for (int nj = 0; nj < 4; ++nj)
      b2f[nj] = *(const s8v*)(wp0 + (size_t)(nj*16)*256 + kb);
#pragma unroll
    for (int mi = 0; mi < 4; ++mi)
#pragma unroll
      for (int nj = 0; nj < 4; ++nj)
        c2[mi][nj] = __builtin_amdgcn_mfma_f32_16x16x32_bf16(a2f[mi], b2f[nj], c2[mi][nj], 0, 0, 0);
  }
  float pb_[4];
#pragma unroll
  for (int nj = 0; nj < 4; ++nj) pb_[nj] = projb[wv*64 + nj*16 + q];
#pragma unroll
  for (int mi = 0; mi < 4; ++mi)
#pragma unroll
    for (int r = 0; r < 4; ++r) {
      int tok = mi*16 + g*4 + r;
      int iy = tok >> 3, ix = tok & 7;
      int oy = (wy*8 + iy + 4) & 127, ox = (wx*8 + ix + 4) & 127;
      size_t rowb = ((((size_t)(bb*128 + oy))*128 + ox) << 8);
#pragma unroll
      for (int nj = 0; nj < 4; ++nj) {
        int ch = wv*64 + nj*16 + q;
        out[rowb + ch] = c2[mi][nj][r] + pb_[nj] + x[rowb + ch];
      }
    }
}

extern "C" void kernel_launch(void* const* d_in, const int* in_sizes, int n_in,
                              void* d_out, int out_size, void* d_ws, size_t ws_size,
                              hipStream_t stream) {
  (void)in_sizes; (void)n_in; (void)out_size; (void)ws_size;
  const float* x     = (const float*)d_in[0];
  const float* mask  = (const float*)d_in[1];
  const float* g     = (const float*)d_in[3];
  const float* bln   = (const float*)d_in[4];
  const float* dww   = (const float*)d_in[5];
  const float* dwb_  = (const float*)d_in[6];
  const float* qkvw  = (const float*)d_in[7];
  const float* qkvb  = (const float*)d_in[8];
  const float* projw = (const float*)d_in[9];
  const float* projb = (const float*)d_in[10];
  const float* rpb   = (const float*)d_in[11];

  // workspace layout (65.5 MiB total):
  unsigned short* wb  = (unsigned short*)d_ws;                       // qkv 393216B + proj 131072B bf16
  float2* musig       = (float2*)((char*)d_ws + 524288);             // 131072 x 8B
  unsigned short* dwb = (unsigned short*)((char*)d_ws + 1572864);    // 64 MiB bf16 window-ordered

  float* outp = (float*)d_out;

  k_wcvt  <<<128,              256, 0, stream>>>(qkvw, projw, wb);
  k_musig <<<32768,            256, 0, stream>>>(x, musig);
  k_dwconv<<<dim3(16,16,32),   256, 0, stream>>>(x, musig, g, bln, dww, dwb_, dwb);
  k_mega  <<<2048,             256, 0, stream>>>(x, musig, g, bln, wb, qkvb,
                                                 wb + 196608, projb, mask, rpb, dwb, outp);
}